// Round 1
// baseline (247.508 us; speedup 1.0000x reference)
//
#include <hip/hip_runtime.h>

#define B 8
#define N 3136          // 56*56
#define C 64
#define CI 32
#define LAM 0.1f
#define HSTEP 0.05f
#define BN_EPS 1e-3f
#define PB 28           // blocks per batch for reduce/iter kernels
#define CHUNK 112       // pixels per block (28*112 = 3136)

// K1: theta = x@Wt + bt, phi = x@Wp + bp   (per-pixel 64->32 matmuls)
// grid: (B*N)/8 blocks of 256; thread = (local pixel p=tid>>5, d=tid&31)
__global__ __launch_bounds__(256) void k_theta_phi(
    const float* __restrict__ x,
    const float* __restrict__ Wt, const float* __restrict__ bt,
    const float* __restrict__ Wp, const float* __restrict__ bp,
    float* __restrict__ theta, float* __restrict__ phi) {
  __shared__ float sWt[64 * 32], sWp[64 * 32], sx[8 * 64];
  const int tid = threadIdx.x;
  for (int i = tid; i < 2048; i += 256) { sWt[i] = Wt[i]; sWp[i] = Wp[i]; }
  const int pix0 = blockIdx.x * 8;
  for (int i = tid; i < 512; i += 256) sx[i] = x[(size_t)pix0 * 64 + i];
  __syncthreads();
  const int p = tid >> 5, d = tid & 31;
  float at = bt[d], ap = bp[d];
  const float* xp = &sx[p * 64];
#pragma unroll
  for (int c = 0; c < 64; ++c) {
    const float xv = xp[c];
    at += xv * sWt[c * 32 + d];
    ap += xv * sWp[c * 32 + d];
  }
  const size_t gp = (size_t)(pix0 + p);
  theta[gp * 32 + d] = at;
  phi[gp * 32 + d] = ap;
}

// K2: M[b][d][c] = sum_n phi[b,n,d]*g[b,n,c];  psum[b][d] = sum_n phi[b,n,d]
// grid: B*PB blocks of 256. Each thread owns k=tid&63, dbase=tid>>6,
// 8 M-entries (d = dbase+4j). LDS-tiled over 8 pixels at a time.
__global__ __launch_bounds__(256) void k_reduce_M(
    const float* __restrict__ phi, const float* __restrict__ g,
    float* __restrict__ M, float* __restrict__ psum) {
  const int b = blockIdx.x / PB, pb = blockIdx.x % PB;
  const int n0 = pb * CHUNK;
  __shared__ float sphi[8 * 32], sg[8 * 64];
  const int tid = threadIdx.x;
  const int k = tid & 63, dbase = tid >> 6;
  float acc[8] = {0.f, 0.f, 0.f, 0.f, 0.f, 0.f, 0.f, 0.f};
  float accp = 0.f;
  const float* phiB = phi + (size_t)b * N * 32;
  const float* gB = g + (size_t)b * N * 64;
  for (int t = 0; t < CHUNK; t += 8) {
    const int n = n0 + t;
    sphi[tid] = phiB[(size_t)n * 32 + tid];            // 8*32 = 256
    sg[tid] = gB[(size_t)n * 64 + tid];                // 8*64 = 512
    sg[tid + 256] = gB[(size_t)n * 64 + tid + 256];
    __syncthreads();
#pragma unroll
    for (int p = 0; p < 8; ++p) {
      const float gv = sg[p * 64 + k];
#pragma unroll
      for (int j = 0; j < 8; ++j)
        acc[j] += sphi[p * 32 + dbase + 4 * j] * gv;
    }
    if (tid < 32) {
#pragma unroll
      for (int p = 0; p < 8; ++p) accp += sphi[p * 32 + tid];
    }
    __syncthreads();
  }
  float* Mb = M + (size_t)b * 2048;
#pragma unroll
  for (int j = 0; j < 8; ++j)
    atomicAdd(&Mb[(dbase + 4 * j) * 64 + k], acc[j]);
  if (tid < 32) atomicAdd(&psum[b * 32 + tid], accp);
}

// K3: one diffusion iteration.
// fg[n,c] = (LAM*theta[n]·M[:,c] - g[n,c]*LAM*theta[n]·psum)/N
// o = BN(fg@Wmat + bvec); relu; out = x + HSTEP*o.
// Optionally accumulates Macc = phi^T @ out (for the next iteration's M).
// grid: B*PB blocks of 256; thread = (p=tid>>6 in 0..3, k=tid&63).
__global__ __launch_bounds__(256) void k_iter(
    const float* __restrict__ x, const float* __restrict__ theta,
    const float* __restrict__ phi, const float* __restrict__ g_in,
    const float* __restrict__ M, const float* __restrict__ psum,
    const float* __restrict__ Wmat, const float* __restrict__ bvec,
    const float* __restrict__ gam, const float* __restrict__ bet,
    const float* __restrict__ mean, const float* __restrict__ var,
    float* __restrict__ out, float* __restrict__ Macc) {
  const int b = blockIdx.x / PB, pb = blockIdx.x % PB;
  const int n0 = pb * CHUNK;
  __shared__ float sM[2048], sW[4096], sps[32];
  __shared__ float sth[4 * 32], sphi[4 * 32];
  __shared__ float sg[4 * 64], sx[4 * 64], sfg[4 * 64], so[4 * 64];
  const int tid = threadIdx.x;
  const int k = tid & 63, p = tid >> 6;  // p == dbase
  for (int i = tid; i < 2048; i += 256) sM[i] = M[(size_t)b * 2048 + i];
  for (int i = tid; i < 4096; i += 256) sW[i] = Wmat[i];
  if (tid < 32) sps[tid] = psum[b * 32 + tid];
  const float scale = gam[k] * rsqrtf(var[k] + BN_EPS);
  const float mu = mean[k], bb = bet[k], bvk = bvec[k];
  __syncthreads();
  float acc[8] = {0.f, 0.f, 0.f, 0.f, 0.f, 0.f, 0.f, 0.f};
  const size_t base = (size_t)b * N;
  for (int t = 0; t < CHUNK; t += 4) {
    const size_t n = base + n0 + t;  // global pixel index of tile start
    if (tid < 128) {
      sth[tid] = theta[n * 32 + tid];   // 4*32
      sphi[tid] = phi[n * 32 + tid];
    }
    sg[tid] = g_in[n * 64 + tid];       // 4*64
    sx[tid] = x[n * 64 + tid];
    __syncthreads();
    // fg for (pixel p, channel k)
    const float* th = &sth[p * 32];
    float fsum = 0.f, fgv = 0.f;
#pragma unroll
    for (int d = 0; d < 32; ++d) {
      const float tv = th[d];
      fsum += tv * sps[d];
      fgv += tv * sM[d * 64 + k];
    }
    fgv = (LAM * fgv - sg[p * 64 + k] * (LAM * fsum)) * (1.0f / (float)N);
    sfg[p * 64 + k] = fgv;
    __syncthreads();
    // o = fg @ Wmat + b, BN, relu, residual
    float o = bvk;
    const float* fgp = &sfg[p * 64];
#pragma unroll
    for (int c = 0; c < 64; ++c) o += fgp[c] * sW[c * 64 + k];
    o = (o - mu) * scale + bb;
    o = fmaxf(o, 0.f);
    const float ov = sx[p * 64 + k] + HSTEP * o;
    out[n * 64 + tid] = ov;
    if (Macc) {  // uniform branch (kernel arg)
      so[tid] = ov;
      __syncthreads();
#pragma unroll
      for (int pp = 0; pp < 4; ++pp) {
        const float ovv = so[pp * 64 + k];
#pragma unroll
        for (int j = 0; j < 8; ++j)
          acc[j] += sphi[pp * 32 + p + 4 * j] * ovv;
      }
    }
    __syncthreads();
  }
  if (Macc) {
    float* Mb = Macc + (size_t)b * 2048;
#pragma unroll
    for (int j = 0; j < 8; ++j)
      atomicAdd(&Mb[(p + 4 * j) * 64 + k], acc[j]);
  }
}

extern "C" void kernel_launch(void* const* d_in, const int* in_sizes, int n_in,
                              void* d_out, int out_size, void* d_ws, size_t ws_size,
                              hipStream_t stream) {
  const float* x    = (const float*)d_in[0];
  const float* Wt   = (const float*)d_in[1];
  const float* bt   = (const float*)d_in[2];
  const float* Wp   = (const float*)d_in[3];
  const float* bp   = (const float*)d_in[4];
  const float* Wst  = (const float*)d_in[5];   // [2,64,64]
  const float* bst  = (const float*)d_in[6];   // [2,64]
  const float* gam  = (const float*)d_in[7];
  const float* bet  = (const float*)d_in[8];
  const float* mean = (const float*)d_in[9];
  const float* var  = (const float*)d_in[10];

  float* ws = (float*)d_ws;
  float* theta = ws;                        // B*N*32 = 802816
  float* phi   = ws + 802816;               // 802816
  float* g1    = ws + 1605632;              // B*N*64 = 1605632
  float* psum  = ws + 3211264;              // B*32 = 256
  float* M0    = ws + 3211520;              // B*2048 = 16384
  float* M1    = ws + 3227904;              // 16384
  // total: 3,244,288 floats ~= 13 MB

  // zero the atomic accumulators (psum, M0, M1 are contiguous)
  hipMemsetAsync(psum, 0, (size_t)(256 + 16384 + 16384) * sizeof(float), stream);

  k_theta_phi<<<(B * N) / 8, 256, 0, stream>>>(x, Wt, bt, Wp, bp, theta, phi);

  // iteration 0 pre-reduce: M0 = phi^T @ x, psum = sum phi
  k_reduce_M<<<B * PB, 256, 0, stream>>>(phi, x, M0, psum);

  // iteration 0: out1 -> g1, fused M1 = phi^T @ out1
  k_iter<<<B * PB, 256, 0, stream>>>(x, theta, phi, x, M0, psum,
                                     Wst, bst, gam, bet, mean, var, g1, M1);

  // iteration 1: out -> d_out (no accumulation)
  k_iter<<<B * PB, 256, 0, stream>>>(x, theta, phi, g1, M1, psum,
                                     Wst + 4096, bst + 64, gam + 64, bet + 64,
                                     mean + 64, var + 64, (float*)d_out, nullptr);
}

// Round 2
// 155.732 us; speedup vs baseline: 1.5893x; 1.5893x over previous
//
#include <hip/hip_runtime.h>

#define B 8
#define N 3136          // 56*56
#define LAM 0.1f
#define HSTEP 0.05f
#define BN_EPS 1e-3f
#define FSC (LAM / 3136.0f)   // lambda/N folded into theta

// K1: theta' = FSC*(x@Wt+bt), phi = x@Wp+bp.
// grid 1568 blocks (16 px each), 256 thr. Lanes 0..31 = theta col, 32..63 = phi col.
__global__ __launch_bounds__(256) void k_theta_phi(
    const float* __restrict__ x,
    const float* __restrict__ Wt, const float* __restrict__ bt,
    const float* __restrict__ Wp, const float* __restrict__ bp,
    float* __restrict__ theta, float* __restrict__ phi) {
  __shared__ float sx[1024];
  const int tid = threadIdx.x;
  const size_t n0 = (size_t)blockIdx.x * 16;
  for (int i = tid; i < 1024; i += 256) sx[i] = x[n0 * 64 + i];
  const int k = tid & 63, p4 = tid >> 6;
  const bool is_t = (k < 32);
  const int d = k & 31;
  const float* __restrict__ Wsrc = is_t ? Wt : Wp;
  float wcol[64];
#pragma unroll
  for (int c = 0; c < 64; ++c) wcol[c] = Wsrc[c * 32 + d];
  const float bias = is_t ? bt[d] : bp[d];
  __syncthreads();
#pragma unroll
  for (int pp = 0; pp < 4; ++pp) {
    const int p = pp * 4 + p4;
    const float* xp = &sx[p * 64];   // broadcast reads (p wave-uniform)
    float a = bias;
#pragma unroll
    for (int c = 0; c < 64; ++c) a += xp[c] * wcol[c];
    const size_t gp = n0 + p;
    if (is_t) theta[gp * 32 + d] = a * FSC;
    else      phi[gp * 32 + d]   = a;
  }
}

// K2: M[b,d,c] += sum_n phi[n,d]*g[n,c]; psum[b,d] += sum_n phi[n,d] (if psum!=null)
// grid 8*98 blocks (32 px each), 256 thr: thread = (k=tid&63, d-slice of 8).
__global__ __launch_bounds__(256) void k_reduce_M(
    const float* __restrict__ phi, const float* __restrict__ g,
    float* __restrict__ M, float* __restrict__ psum) {
  const int b = blockIdx.x / 98, pb = blockIdx.x % 98;
  const size_t n0 = (size_t)b * N + (size_t)pb * 32;
  __shared__ float sphi[1024], sg[2048];
  const int tid = threadIdx.x;
  for (int i = tid; i < 1024; i += 256) sphi[i] = phi[n0 * 32 + i];
  for (int i = tid; i < 2048; i += 256) sg[i] = g[n0 * 64 + i];
  __syncthreads();
  const int k = tid & 63, d8 = (tid >> 6) * 8;
  float acc[8] = {0.f, 0.f, 0.f, 0.f, 0.f, 0.f, 0.f, 0.f};
#pragma unroll
  for (int p = 0; p < 32; ++p) {
    const float gv = sg[p * 64 + k];          // 2-way aliasing: free
    const float* ph = &sphi[p * 32 + d8];     // contiguous 8 -> b128 pair
#pragma unroll
    for (int j = 0; j < 8; ++j) acc[j] += ph[j] * gv;
  }
  float* Mb = M + (size_t)b * 2048;
#pragma unroll
  for (int j = 0; j < 8; ++j) atomicAdd(&Mb[(d8 + j) * 64 + k], acc[j]);
  if (psum != nullptr && tid < 32) {
    float a = 0.f;
#pragma unroll
    for (int p = 0; p < 32; ++p) a += sphi[p * 32 + tid];
    atomicAdd(&psum[b * 32 + tid], a);
  }
}

// K3: MW[b,d,k] = sum_c M[b,d,c] * W[c,k] * scale[k]   (BN scale folded)
// grid B=8 blocks, 256 thr.
__global__ __launch_bounds__(256) void k_mw(
    const float* __restrict__ M, const float* __restrict__ Wmat,
    const float* __restrict__ gam, const float* __restrict__ var,
    float* __restrict__ MW) {
  __shared__ float sM[2048], sW[4096];
  const int tid = threadIdx.x, b = blockIdx.x;
  for (int i = tid; i < 2048; i += 256) sM[i] = M[(size_t)b * 2048 + i];
  for (int i = tid; i < 4096; i += 256) {
    const int kk = i & 63;
    sW[i] = Wmat[i] * gam[kk] * rsqrtf(var[kk] + BN_EPS);
  }
  __syncthreads();
  const int k = tid & 63, d8 = (tid >> 6) * 8;
  float acc[8] = {0.f, 0.f, 0.f, 0.f, 0.f, 0.f, 0.f, 0.f};
#pragma unroll
  for (int c = 0; c < 64; ++c) {
    const float wv = sW[c * 64 + k];
#pragma unroll
    for (int j = 0; j < 8; ++j) acc[j] += sM[(d8 + j) * 64 + c] * wv;
  }
  float* out = MW + (size_t)b * 2048;
#pragma unroll
  for (int j = 0; j < 8; ++j) out[(d8 + j) * 64 + k] = acc[j];
}

// K4: out[n,k] = x[n,k] + 0.05*relu( th'·MW[:,k] - (th'·ps)*(g·W'[:,k]) + b'[k] )
// grid 8*196 blocks (16 px each), 256 thr = (p4=tid>>6, k=tid&63).
// W'/MW columns register-cached from coalesced global (L1-resident).
__global__ __launch_bounds__(256) void k_iter(
    const float* __restrict__ x, const float* __restrict__ theta,
    const float* __restrict__ g_in,
    const float* __restrict__ MW, const float* __restrict__ psum,
    const float* __restrict__ Wmat, const float* __restrict__ bvec,
    const float* __restrict__ gam, const float* __restrict__ bet,
    const float* __restrict__ mean, const float* __restrict__ var,
    float* __restrict__ out) {
  const int bb = blockIdx.x / 196, pb = blockIdx.x % 196;
  const size_t n0 = (size_t)bb * N + (size_t)pb * 16;
  __shared__ float sth[512], sg[1024], sx[1024], sps[32];
  const int tid = threadIdx.x;
  const int k = tid & 63, p4 = tid >> 6;
  for (int i = tid; i < 512; i += 256) sth[i] = theta[n0 * 32 + i];
  for (int i = tid; i < 1024; i += 256) {
    sg[i] = g_in[n0 * 64 + i];
    sx[i] = x[n0 * 64 + i];
  }
  if (tid < 32) sps[tid] = psum[bb * 32 + tid];
  const float scale = gam[k] * rsqrtf(var[k] + BN_EPS);
  const float bpk = (bvec[k] - mean[k]) * scale + bet[k];
  float wcol[64], mwcol[32];
#pragma unroll
  for (int c = 0; c < 64; ++c) wcol[c] = Wmat[c * 64 + k] * scale;  // coalesced
#pragma unroll
  for (int d = 0; d < 32; ++d) mwcol[d] = MW[(size_t)bb * 2048 + d * 64 + k];
  __syncthreads();
#pragma unroll
  for (int pp = 0; pp < 4; ++pp) {
    const int p = pp * 4 + p4;
    const float* th = &sth[p * 32];   // broadcast (p wave-uniform)
    float t1 = 0.f, s = 0.f;
#pragma unroll
    for (int d = 0; d < 32; ++d) {
      const float tv = th[d];
      t1 += tv * mwcol[d];
      s  += tv * sps[d];
    }
    const float* gp = &sg[p * 64];    // broadcast
    float d2 = 0.f;
#pragma unroll
    for (int c = 0; c < 64; ++c) d2 += gp[c] * wcol[c];
    float o = t1 - s * d2 + bpk;
    o = fmaxf(o, 0.f);
    out[(n0 + p) * 64 + k] = sx[p * 64 + k] + HSTEP * o;
  }
}

extern "C" void kernel_launch(void* const* d_in, const int* in_sizes, int n_in,
                              void* d_out, int out_size, void* d_ws, size_t ws_size,
                              hipStream_t stream) {
  const float* x    = (const float*)d_in[0];
  const float* Wt   = (const float*)d_in[1];
  const float* bt   = (const float*)d_in[2];
  const float* Wp   = (const float*)d_in[3];
  const float* bp   = (const float*)d_in[4];
  const float* Wst  = (const float*)d_in[5];   // [2,64,64]
  const float* bst  = (const float*)d_in[6];   // [2,64]
  const float* gam  = (const float*)d_in[7];
  const float* bet  = (const float*)d_in[8];
  const float* mean = (const float*)d_in[9];
  const float* var  = (const float*)d_in[10];

  float* ws = (float*)d_ws;
  float* theta = ws;                  // B*N*32 = 802816
  float* phi   = ws + 802816;         // 802816
  float* g1    = ws + 1605632;        // B*N*64 = 1605632
  float* psum  = ws + 3211264;        // B*32 = 256
  float* M0    = ws + 3211520;        // B*2048 = 16384
  float* M1    = ws + 3227904;        // B*2048 = 16384
  float* MW0   = M1;                  // alias: M1 region free until 2nd reduce
  float* MW1   = M0;                  // alias: M0 dead after 1st k_mw
  // total = 3,244,288 floats = 12.98 MB (same footprint as round 1)

  // zero atomic accumulators for iteration 0 (psum + M0, contiguous)
  hipMemsetAsync(psum, 0, (size_t)(256 + 16384) * sizeof(float), stream);

  k_theta_phi<<<1568, 256, 0, stream>>>(x, Wt, bt, Wp, bp, theta, phi);
  k_reduce_M<<<784, 256, 0, stream>>>(phi, x, M0, psum);
  k_mw<<<8, 256, 0, stream>>>(M0, Wst, gam, var, MW0);
  k_iter<<<1568, 256, 0, stream>>>(x, theta, x, MW0, psum,
                                   Wst, bst, gam, bet, mean, var, g1);

  // MW0 (= M1 region) is dead now; zero it for the 2nd reduce's atomics
  hipMemsetAsync(M1, 0, (size_t)16384 * sizeof(float), stream);
  k_reduce_M<<<784, 256, 0, stream>>>(phi, g1, M1, nullptr);
  k_mw<<<8, 256, 0, stream>>>(M1, Wst + 4096, gam + 64, var + 64, MW1);
  k_iter<<<1568, 256, 0, stream>>>(x, theta, g1, MW1, psum,
                                   Wst + 4096, bst + 64, gam + 64, bet + 64,
                                   mean + 64, var + 64, (float*)d_out);
}